// Round 1
// baseline (850.807 us; speedup 1.0000x reference)
//
#include <hip/hip_runtime.h>

#define HH 16
#define SS 4096
#define DHD 128
#define BR 128        // q rows per block (32 per wave)
#define BC 64         // k/v rows per tile
#define LDQ 136       // row length (bf16) for q_s/k_s staging: 272B, 16B-aligned, +pad
#define LDV 68        // row length for vt_s: 136B = 34 banks -> 2-way (free) on d=lane writes
#define LDP 72        // row length for p_s: 144B, 16B-aligned

typedef __bf16 bf16x8_t __attribute__((ext_vector_type(8)));
typedef __bf16 bf16x4_t __attribute__((ext_vector_type(4)));
typedef float  f32x4_t  __attribute__((ext_vector_type(4)));

__device__ __forceinline__ unsigned short f2b(float f) {
    union { float f; unsigned u; } x; x.f = f;
    unsigned r = x.u + 0x7fffu + ((x.u >> 16) & 1u);   // RNE
    return (unsigned short)(r >> 16);
}

__global__ __launch_bounds__(256, 2)
void fa_fwd(const float* __restrict__ q, const float* __restrict__ k,
            const float* __restrict__ v, float* __restrict__ out)
{
    // Linear block id L; pair L and L+256 -> qt and 31-qt so co-resident blocks
    // on one CU sum to a constant 66 k-tile iterations (causal load balance).
    const int L  = blockIdx.x;
    const int h  = L & 15;
    const int g  = L >> 4;                 // 0..31
    const int qt = (g < 16) ? g : 47 - g;  // 0..31

    const int tid  = threadIdx.x;
    const int wave = tid >> 6;
    const int lane = tid & 63;
    const int l16  = lane & 15;
    const int quad = lane >> 4;

    __shared__ __align__(16) unsigned short qp_s[BR * LDQ];  // Q staging, then P scratch
    __shared__ __align__(16) unsigned short k_s [BC * LDQ];
    __shared__ __align__(16) unsigned short vt_s[DHD * LDV]; // vt_s[d][s] transposed

    const size_t hoff = (size_t)h * SS * DHD;
    const float* qh = q + hoff;
    const float* kh = k + hoff;
    const float* vh = v + hoff;

    // ---- stage Q tile (BR x 128 fp32 -> bf16, row-major) ----
    #pragma unroll
    for (int i = 0; i < 16; ++i) {
        int idx = tid + i * 256;           // 0..4095
        int r   = idx >> 5;
        int c4  = idx & 31;
        float4 val = ((const float4*)(qh + (size_t)(qt * BR + r) * DHD))[c4];
        ushort4 u;
        u.x = f2b(val.x); u.y = f2b(val.y); u.z = f2b(val.z); u.w = f2b(val.w);
        *(ushort4*)&qp_s[r * LDQ + c4 * 4] = u;
    }
    __syncthreads();

    // ---- Q A-fragments into registers: wave owns rows wave*32 .. +32 ----
    bf16x8_t qf[2][4];
    #pragma unroll
    for (int mt = 0; mt < 2; ++mt)
        #pragma unroll
        for (int kc = 0; kc < 4; ++kc)
            qf[mt][kc] = *(const bf16x8_t*)
                &qp_s[(wave*32 + mt*16 + l16) * LDQ + kc*32 + quad*8];

    f32x4_t oacc[2][8];
    #pragma unroll
    for (int mt = 0; mt < 2; ++mt)
        #pragma unroll
        for (int fo = 0; fo < 8; ++fo) oacc[mt][fo] = (f32x4_t)(0.0f);

    float mi[2][4], li[2][4];
    #pragma unroll
    for (int mt = 0; mt < 2; ++mt)
        #pragma unroll
        for (int r = 0; r < 4; ++r) { mi[mt][r] = -INFINITY; li[mt][r] = 0.0f; }

    const float scale = 0.088388347648318447f;   // 1/sqrt(128)
    const int jmax  = 2*qt + 1;
    const int dbase = (wave & 1) * 64;     // V-transpose staging split
    const int rbase = (wave >> 1) * 32;

    for (int j = 0; j <= jmax; ++j) {
        __syncthreads();                   // prev-iter LDS reads done before restage
        // ---- stage K tile (row-major bf16) ----
        #pragma unroll
        for (int i = 0; i < 8; ++i) {
            int idx = tid + i * 256;       // 0..2047
            int r   = idx >> 5;
            int c4  = idx & 31;
            float4 val = ((const float4*)(kh + (size_t)(j * BC + r) * DHD))[c4];
            ushort4 u;
            u.x = f2b(val.x); u.y = f2b(val.y); u.z = f2b(val.z); u.w = f2b(val.w);
            *(ushort4*)&k_s[r * LDQ + c4 * 4] = u;
        }
        // ---- stage V transposed: lane owns column d = dbase+lane ----
        #pragma unroll
        for (int p = 0; p < 8; ++p) {
            int r0 = rbase + p * 4;
            const float* vp = vh + (size_t)(j * BC + r0) * DHD + dbase + lane;
            float a0 = vp[0], a1 = vp[DHD], a2 = vp[2*DHD], a3 = vp[3*DHD];
            ushort4 u;
            u.x = f2b(a0); u.y = f2b(a1); u.z = f2b(a2); u.w = f2b(a3);
            *(ushort4*)&vt_s[(dbase + lane) * LDV + r0] = u;
        }
        __syncthreads();

        // ---- S = Q K^T : per wave 32x64, K-frags reused across 2 m-tiles ----
        f32x4_t sa[2][4];
        #pragma unroll
        for (int mt = 0; mt < 2; ++mt)
            #pragma unroll
            for (int n = 0; n < 4; ++n) sa[mt][n] = (f32x4_t)(0.0f);
        #pragma unroll
        for (int kc = 0; kc < 4; ++kc) {
            #pragma unroll
            for (int n = 0; n < 4; ++n) {
                bf16x8_t bf = *(const bf16x8_t*)
                    &k_s[(n*16 + l16) * LDQ + kc*32 + quad*8];
                sa[0][n] = __builtin_amdgcn_mfma_f32_16x16x32_bf16(qf[0][kc], bf, sa[0][n], 0, 0, 0);
                sa[1][n] = __builtin_amdgcn_mfma_f32_16x16x32_bf16(qf[1][kc], bf, sa[1][n], 0, 0, 0);
            }
        }

        // ---- scale + causal mask (C layout: row=quad*4+reg, col=n*16+l16) ----
        const bool need_mask = (j >= 2*qt);
        #pragma unroll
        for (int mt = 0; mt < 2; ++mt)
            #pragma unroll
            for (int n = 0; n < 4; ++n)
                #pragma unroll
                for (int r = 0; r < 4; ++r) {
                    float sv = sa[mt][n][r] * scale;
                    if (need_mask) {
                        int grow = wave*32 + mt*16 + quad*4 + r;     // + qt*128 implicit
                        int gcol = (j - 2*qt)*64 + n*16 + l16;
                        if (gcol > grow) sv = -INFINITY;
                    }
                    sa[mt][n][r] = sv;
                }

        // ---- online softmax (rows live in 16-lane groups sharing `quad`) ----
        float alpha[2][4];
        #pragma unroll
        for (int mt = 0; mt < 2; ++mt)
            #pragma unroll
            for (int r = 0; r < 4; ++r) {
                float mx = fmaxf(fmaxf(sa[mt][0][r], sa[mt][1][r]),
                                 fmaxf(sa[mt][2][r], sa[mt][3][r]));
                mx = fmaxf(mx, __shfl_xor(mx, 1));
                mx = fmaxf(mx, __shfl_xor(mx, 2));
                mx = fmaxf(mx, __shfl_xor(mx, 4));
                mx = fmaxf(mx, __shfl_xor(mx, 8));
                float mnew = fmaxf(mi[mt][r], mx);
                float a = __expf(mi[mt][r] - mnew);
                mi[mt][r] = mnew;
                float rs = 0.0f;
                #pragma unroll
                for (int n = 0; n < 4; ++n) {
                    float pv = __expf(sa[mt][n][r] - mnew);
                    sa[mt][n][r] = pv;
                    rs += pv;
                }
                rs += __shfl_xor(rs, 1);
                rs += __shfl_xor(rs, 2);
                rs += __shfl_xor(rs, 4);
                rs += __shfl_xor(rs, 8);
                li[mt][r] = li[mt][r] * a + rs;
                alpha[mt][r] = a;
            }

        // ---- P -> LDS (C layout -> A layout round-trip), rescale O ----
        #pragma unroll
        for (int mt = 0; mt < 2; ++mt)
            #pragma unroll
            for (int n = 0; n < 4; ++n)
                #pragma unroll
                for (int r = 0; r < 4; ++r)
                    qp_s[(wave*32 + mt*16 + quad*4 + r) * LDP + n*16 + l16] =
                        f2b(sa[mt][n][r]);

        #pragma unroll
        for (int mt = 0; mt < 2; ++mt)
            #pragma unroll
            for (int fo = 0; fo < 8; ++fo)
                #pragma unroll
                for (int r = 0; r < 4; ++r)
                    oacc[mt][fo][r] *= alpha[mt][r];

        // ---- O += P V (V-frags reused across 2 m-tiles; wave-local p region,
        //      same-wave DS ordering makes this barrier-free) ----
        #pragma unroll
        for (int kc = 0; kc < 2; ++kc) {
            bf16x8_t pa0 = *(const bf16x8_t*)
                &qp_s[(wave*32 + l16) * LDP + kc*32 + quad*8];
            bf16x8_t pa1 = *(const bf16x8_t*)
                &qp_s[(wave*32 + 16 + l16) * LDP + kc*32 + quad*8];
            #pragma unroll
            for (int fo = 0; fo < 8; ++fo) {
                bf16x4_t blo = *(const bf16x4_t*)
                    &vt_s[(fo*16 + l16) * LDV + kc*32 + quad*8];
                bf16x4_t bhi = *(const bf16x4_t*)
                    &vt_s[(fo*16 + l16) * LDV + kc*32 + quad*8 + 4];
                bf16x8_t bf = __builtin_shufflevector(blo, bhi, 0,1,2,3,4,5,6,7);
                oacc[0][fo] = __builtin_amdgcn_mfma_f32_16x16x32_bf16(pa0, bf, oacc[0][fo], 0, 0, 0);
                oacc[1][fo] = __builtin_amdgcn_mfma_f32_16x16x32_bf16(pa1, bf, oacc[1][fo], 0, 0, 0);
            }
        }
    }

    // ---- epilogue: O / l, write (S, H*DH) fp32 ----
    float* outp = out + (size_t)(qt * BR) * (HH * DHD) + h * DHD;
    #pragma unroll
    for (int mt = 0; mt < 2; ++mt) {
        float inv[4];
        #pragma unroll
        for (int r = 0; r < 4; ++r) inv[r] = 1.0f / li[mt][r];
        #pragma unroll
        for (int fo = 0; fo < 8; ++fo)
            #pragma unroll
            for (int r = 0; r < 4; ++r) {
                int row = wave*32 + mt*16 + quad*4 + r;
                outp[(size_t)row * (HH * DHD) + fo*16 + l16] = oacc[mt][fo][r] * inv[r];
            }
    }
}

extern "C" void kernel_launch(void* const* d_in, const int* in_sizes, int n_in,
                              void* d_out, int out_size, void* d_ws, size_t ws_size,
                              hipStream_t stream) {
    const float* q = (const float*)d_in[0];
    const float* k = (const float*)d_in[1];
    const float* v = (const float*)d_in[2];
    float* out = (float*)d_out;
    // grid: 512 blocks = (SS/BR) * HH, 1-D for the load-balancing id pairing
    fa_fwd<<<dim3((SS / BR) * HH), dim3(256), 0, stream>>>(q, k, v, out);
}

// Round 2
// 369.774 us; speedup vs baseline: 2.3009x; 2.3009x over previous
//
#include <hip/hip_runtime.h>

#define HH 16
#define SS 4096
#define DHD 128
#define BR 64         // q rows per block (16 per wave)
#define BC 64         // k/v rows per tile
#define LDQ 136       // row length (bf16) for q_s/k_s: 272B, 16B-aligned, +pad
#define LDV 68        // row length for vt_s
#define LDP 72        // row length for p_s: 144B, 16B-aligned

typedef __bf16 bf16x8_t __attribute__((ext_vector_type(8)));
typedef __bf16 bf16x4_t __attribute__((ext_vector_type(4)));
typedef float  f32x4_t  __attribute__((ext_vector_type(4)));

__global__ __launch_bounds__(256, 2)
void fa_fwd(const float* __restrict__ q, const float* __restrict__ k,
            const float* __restrict__ v, float* __restrict__ out)
{
    // Each block handles q-tiles {g, 63-g}: (g+1)+(64-g) = 65 k-tile iters for
    // every block -> 512 equal blocks, stable 2 blocks/CU co-residency.
    const int L = blockIdx.x;
    const int h = L & 15;
    const int g = L >> 4;              // 0..31
    const int qts[2] = { g, 63 - g };

    const int tid  = threadIdx.x;
    const int wave = tid >> 6;
    const int lane = tid & 63;
    const int l16  = lane & 15;
    const int quad = lane >> 4;
    const int rK   = tid >> 5;         // K/Q staging row base (0..7)
    const int c4   = tid & 31;         // K/Q staging float4 col
    const int dbase = (wave & 1) * 64; // V-transpose staging split
    const int rbase = (wave >> 1) * 32;

    __shared__ __align__(16) unsigned short qp_s[BR * LDQ];  // Q staging, then P scratch
    __shared__ __align__(16) unsigned short k_s [BC * LDQ];
    __shared__ __align__(16) unsigned short vt_s[DHD * LDV]; // vt_s[d][s]

    const size_t hoff = (size_t)h * SS * DHD;
    const float* qh = q + hoff;
    const float* kh = k + hoff;
    const float* vh = v + hoff;

    // ---- K/V register prefetch buffers (in flight across compute) ----
    float4 kreg[8];
    float  vreg[8][4];

    auto issue = [&](int j) {
        const float* kb = kh + (size_t)j * BC * DHD;
        #pragma unroll
        for (int i = 0; i < 8; ++i)
            kreg[i] = ((const float4*)(kb + (size_t)(rK + i * 8) * DHD))[c4];
        const float* vb = vh + (size_t)j * BC * DHD + dbase + lane;
        #pragma unroll
        for (int p = 0; p < 8; ++p) {
            const float* vp = vb + (size_t)(rbase + p * 4) * DHD;
            vreg[p][0] = vp[0];
            vreg[p][1] = vp[DHD];
            vreg[p][2] = vp[2 * DHD];
            vreg[p][3] = vp[3 * DHD];
        }
    };

    const float scale = 0.088388347648318447f;   // 1/sqrt(128)

    issue(0);

    for (int t = 0; t < 2; ++t) {
        const int qt = qts[t];
        __syncthreads();               // prior tile's qp_s reads complete
        // ---- stage Q tile ----
        #pragma unroll
        for (int i = 0; i < 8; ++i) {
            int r = rK + i * 8;
            float4 val = ((const float4*)(qh + (size_t)(qt * BR + r) * DHD))[c4];
            bf16x4_t b;
            b[0] = (__bf16)val.x; b[1] = (__bf16)val.y;
            b[2] = (__bf16)val.z; b[3] = (__bf16)val.w;
            *(bf16x4_t*)&qp_s[r * LDQ + c4 * 4] = b;
        }
        __syncthreads();

        // ---- Q A-fragments: wave owns rows wave*16 .. +16 ----
        bf16x8_t qf[4];
        #pragma unroll
        for (int kc = 0; kc < 4; ++kc)
            qf[kc] = *(const bf16x8_t*)
                &qp_s[(wave * 16 + l16) * LDQ + kc * 32 + quad * 8];

        f32x4_t oacc[8];
        #pragma unroll
        for (int fo = 0; fo < 8; ++fo) oacc[fo] = (f32x4_t)(0.0f);
        float mi[4], li[4];
        #pragma unroll
        for (int r = 0; r < 4; ++r) { mi[r] = -INFINITY; li[r] = 0.0f; }

        for (int j = 0; j <= qt; ++j) {
            __syncthreads();           // prev-iter LDS reads done; qf loaded
            // ---- commit prefetched K (row-major bf16) ----
            #pragma unroll
            for (int i = 0; i < 8; ++i) {
                bf16x4_t b;
                b[0] = (__bf16)kreg[i].x; b[1] = (__bf16)kreg[i].y;
                b[2] = (__bf16)kreg[i].z; b[3] = (__bf16)kreg[i].w;
                *(bf16x4_t*)&k_s[(rK + i * 8) * LDQ + c4 * 4] = b;
            }
            // ---- commit prefetched V transposed ----
            #pragma unroll
            for (int p = 0; p < 8; ++p) {
                bf16x4_t b;
                b[0] = (__bf16)vreg[p][0]; b[1] = (__bf16)vreg[p][1];
                b[2] = (__bf16)vreg[p][2]; b[3] = (__bf16)vreg[p][3];
                *(bf16x4_t*)&vt_s[(dbase + lane) * LDV + rbase + p * 4] = b;
            }
            // ---- issue next tile's global loads (overlap with compute) ----
            if (j < qt)       issue(j + 1);
            else if (t == 0)  issue(0);
            __syncthreads();

            // ---- S = Q K^T : 16x64 per wave ----
            f32x4_t sa[4];
            #pragma unroll
            for (int n = 0; n < 4; ++n) sa[n] = (f32x4_t)(0.0f);
            #pragma unroll
            for (int kc = 0; kc < 4; ++kc)
                #pragma unroll
                for (int n = 0; n < 4; ++n) {
                    bf16x8_t bf = *(const bf16x8_t*)
                        &k_s[(n * 16 + l16) * LDQ + kc * 32 + quad * 8];
                    sa[n] = __builtin_amdgcn_mfma_f32_16x16x32_bf16(qf[kc], bf, sa[n], 0, 0, 0);
                }

            // ---- scale + causal mask + online softmax ----
            const bool nm = (j == qt);
            float alpha[4];
            #pragma unroll
            for (int r = 0; r < 4; ++r) {
                #pragma unroll
                for (int n = 0; n < 4; ++n) {
                    float sv = sa[n][r] * scale;
                    if (nm) {
                        int grow = wave * 16 + quad * 4 + r;
                        int gcol = n * 16 + l16;
                        if (gcol > grow) sv = -INFINITY;
                    }
                    sa[n][r] = sv;
                }
                float mx = fmaxf(fmaxf(sa[0][r], sa[1][r]),
                                 fmaxf(sa[2][r], sa[3][r]));
                mx = fmaxf(mx, __shfl_xor(mx, 1));
                mx = fmaxf(mx, __shfl_xor(mx, 2));
                mx = fmaxf(mx, __shfl_xor(mx, 4));
                mx = fmaxf(mx, __shfl_xor(mx, 8));
                float mnew = fmaxf(mi[r], mx);
                float a = __expf(mi[r] - mnew);
                mi[r] = mnew;
                float rs = 0.0f;
                #pragma unroll
                for (int n = 0; n < 4; ++n) {
                    float pv = __expf(sa[n][r] - mnew);
                    sa[n][r] = pv;
                    rs += pv;
                }
                rs += __shfl_xor(rs, 1);
                rs += __shfl_xor(rs, 2);
                rs += __shfl_xor(rs, 4);
                rs += __shfl_xor(rs, 8);
                li[r] = li[r] * a + rs;
                alpha[r] = a;
            }

            // ---- P -> LDS (C->A layout round-trip; wave-local rows) ----
            #pragma unroll
            for (int n = 0; n < 4; ++n)
                #pragma unroll
                for (int r = 0; r < 4; ++r)
                    ((__bf16*)qp_s)[(wave * 16 + quad * 4 + r) * LDP + n * 16 + l16] =
                        (__bf16)sa[n][r];

            #pragma unroll
            for (int fo = 0; fo < 8; ++fo)
                #pragma unroll
                for (int r = 0; r < 4; ++r)
                    oacc[fo][r] *= alpha[r];

            // ---- O += P V ----
            #pragma unroll
            for (int kc = 0; kc < 2; ++kc) {
                bf16x8_t pa = *(const bf16x8_t*)
                    &qp_s[(wave * 16 + l16) * LDP + kc * 32 + quad * 8];
                #pragma unroll
                for (int fo = 0; fo < 8; ++fo) {
                    bf16x4_t blo = *(const bf16x4_t*)
                        &vt_s[(fo * 16 + l16) * LDV + kc * 32 + quad * 8];
                    bf16x4_t bhi = *(const bf16x4_t*)
                        &vt_s[(fo * 16 + l16) * LDV + kc * 32 + quad * 8 + 4];
                    bf16x8_t bf = __builtin_shufflevector(blo, bhi, 0,1,2,3,4,5,6,7);
                    oacc[fo] = __builtin_amdgcn_mfma_f32_16x16x32_bf16(pa, bf, oacc[fo], 0, 0, 0);
                }
            }
        }

        // ---- epilogue for this tile ----
        float* outp = out + (size_t)(qt * BR) * (HH * DHD) + h * DHD;
        float inv[4];
        #pragma unroll
        for (int r = 0; r < 4; ++r) inv[r] = 1.0f / li[r];
        #pragma unroll
        for (int fo = 0; fo < 8; ++fo)
            #pragma unroll
            for (int r = 0; r < 4; ++r) {
                int row = wave * 16 + quad * 4 + r;
                outp[(size_t)row * (HH * DHD) + fo * 16 + l16] = oacc[fo][r] * inv[r];
            }
    }
}

extern "C" void kernel_launch(void* const* d_in, const int* in_sizes, int n_in,
                              void* d_out, int out_size, void* d_ws, size_t ws_size,
                              hipStream_t stream) {
    const float* q = (const float*)d_in[0];
    const float* k = (const float*)d_in[1];
    const float* v = (const float*)d_in[2];
    float* out = (float*)d_out;
    fa_fwd<<<dim3((SS / BR) * HH / 2), dim3(256), 0, stream>>>(q, k, v, out);
}